// Round 6
// baseline (117.190 us; speedup 1.0000x reference)
//
#include <hip/hip_runtime.h>
#include <math.h>

// AFM forward: out[b] = linear(b) + softmax-weighted pair-interaction projection.
// B=4096, F=26, d=64, P=325 pairs, af=64.
//
// R13: two-phase softmax -- the serial online-softmax recurrence is deleted.
// R12 post-mortem: doubling wave supply (32/CU) did NOT shrink afm (113.4 vs
// 110.4 total; second null-TLP datapoint after R9) => the binding constraint
// is the per-wave serial chain threading all 21 tiles (m,l,acc recurrence),
// which extra waves cannot shorten. Logits are small (w2·relu(W1^T x), x ~
// 5e-3 scale) and each lane owns only 21 of them, so:
//   Phase 1: 21 INDEPENDENT tiles -> lg[21] in registers (no cross-tile dep;
//            all tiles' LDS loads + MFMAs free to overlap).
//   Softmax: one per-lane max tree + 4 ln-shfls + 21 exps + partial-tree sum.
//   Phase 2: re-gather x from LDS, acc += e_k * x_k into even/odd split
//            accumulators (10-deep pk_fma chains, no global recurrence).
// Structure otherwise = R11 (best, 110.4): 1 row/wave, 4 waves/block, grid
// 1024, block-cooperative prologue, permlane qd_sum, launch_bounds(256,2)
// (R10 lesson: spills are the enemy; cap 256 VGPR).

#define NF 26
#define NP 325
#define NMT 21           // 21 m-tiles of 16 pairs (336, pads -> -inf)
#define ED 64
#define AF 64
#define NDENSE 13
#define WPB 4            // waves (rows) per block
#define BLOCK (WPB * 64)
#define ESTRIDE 72       // f16 elems per emb row: 144 B (16B-aligned rows)
#define WSTRIDE 72       // f16 elems per w1t row: 144 B (16B-aligned rows)

typedef __attribute__((ext_vector_type(8))) _Float16 half8;
typedef __attribute__((ext_vector_type(4))) float f32x4;

__device__ __forceinline__ half8 bcast8(float v) {
    _Float16 hh = (_Float16)v;
    half8 r = { hh, hh, hh, hh, hh, hh, hh, hh };
    return r;
}

// Sum across the qd lane-groups (lane bits 4,5). permlane*_swap runs on the
// VALU pipe (no lgkmcnt interaction); swap(x,x) returns (even-group bcast,
// odd-group bcast), so r0+r1 = xor-sum, uniform across lanes.
__device__ __forceinline__ float qd_sum(float x) {
#if __has_builtin(__builtin_amdgcn_permlane16_swap) && __has_builtin(__builtin_amdgcn_permlane32_swap)
    {
        auto a = __builtin_amdgcn_permlane16_swap(__builtin_bit_cast(unsigned, x),
                                                  __builtin_bit_cast(unsigned, x),
                                                  false, false);
        x = __builtin_bit_cast(float, a[0]) + __builtin_bit_cast(float, a[1]);
        auto b = __builtin_amdgcn_permlane32_swap(__builtin_bit_cast(unsigned, x),
                                                  __builtin_bit_cast(unsigned, x),
                                                  false, false);
        x = __builtin_bit_cast(float, b[0]) + __builtin_bit_cast(float, b[1]);
    }
#else
    x += __shfl_xor(x, 16, 64);
    x += __shfl_xor(x, 32, 64);
#endif
    return x;
}

__global__ __launch_bounds__(BLOCK, 2)   // cap 256 VGPR: spills are the enemy (R10)
void afm_kernel(const int*   __restrict__ sparse,   // [B,26]
                const float* __restrict__ dense,    // [B,13]
                const float* __restrict__ etab,     // [V,64]
                const float* __restrict__ ltab,     // [V]
                const float* __restrict__ wdense,   // [13]
                const float* __restrict__ bias,     // [1]
                const float* __restrict__ W1,       // [64][64] f32, d-major
                const float* __restrict__ b1,       // [64]
                const float* __restrict__ w2,       // [64]
                const float* __restrict__ proj,     // [64]
                float*       __restrict__ out,      // [B]
                int B)
{
    const int t    = threadIdx.x;
    const int wave = t >> 6;
    const int lane = t & 63;
    const int qd   = lane >> 4;     // quad 0..3
    const int ln   = lane & 15;

    __shared__ alignas(16) _Float16       w1t_s[AF][WSTRIDE];        // 9216 B
    __shared__              unsigned short tab_s[NMT * 16];          //  672 B
    __shared__ alignas(16) _Float16       emb_all[WPB][NF][ESTRIDE]; // 14976 B

    // ---- block-cooperative embedding staging: WPB rows spread evenly over
    //      256 threads (832 tasks), f32 gather -> f16 b128 LDS writes ----
    for (int task = t; task < WPB * NF * 8; task += BLOCK) {
        int w   = task / (NF * 8);
        int rem = task - w * (NF * 8);
        int f = rem >> 3, c = rem & 7;                   // 8-half chunk
        int rw = blockIdx.x * WPB + w;
        if (rw < B) {
            const float* src = etab + (size_t)sparse[rw * NF + f] * ED + c * 8;
            float4 v0 = *(const float4*)(src);
            float4 v1 = *(const float4*)(src + 4);
            half8 hv = { (_Float16)v0.x, (_Float16)v0.y, (_Float16)v0.z, (_Float16)v0.w,
                         (_Float16)v1.x, (_Float16)v1.y, (_Float16)v1.z, (_Float16)v1.w };
            *(half8*)(&emb_all[w][f][c * 8]) = hv;
        }
    }
    // ---- block-cooperative W1 -> W1^T staging (L2-hot 16 KB) ----
    for (int idx = t; idx < ED * AF; idx += BLOCK) {
        int d = idx >> 6, a = idx & 63;       // W1 is [d][a]
        w1t_s[a][d] = (_Float16)W1[idx];
    }
    // ---- pair-index table: tab_s[p] = i | j<<8 (slots >= NP stay 0) ----
    for (int p = t; p < NMT * 16; p += BLOCK) {
        unsigned short v = 0;
        if (p < NP) {
            int rem = p, i = 0;
            while (rem >= NF - 1 - i) { rem -= NF - 1 - i; ++i; }
            v = (unsigned short)(i | ((i + 1 + rem) << 8));
        }
        tab_s[p] = v;
    }

    const int r = blockIdx.x * WPB + wave;   // this wave's batch row
    const bool active = (r < B);

    _Float16 (* __restrict__ emb)[ESTRIDE] = emb_all[wave];

    __syncthreads();          // w1t_s/tab_s/emb_all visible
    if (!active) return;      // safe: no barriers after this point

    // b1/w2 for af = nt*16 + qd*4 + rr  (C-row mapping)
    float4 b1v4[4], w2v4[4];
    #pragma unroll
    for (int nt = 0; nt < 4; ++nt) {
        b1v4[nt] = *(const float4*)(b1 + nt * 16 + qd * 4);
        w2v4[nt] = *(const float4*)(w2 + nt * 16 + qd * 4);
    }

    // ---- W1^T A-operand fragments from LDS:
    //      bfr[nt][kh] = w1t[af = nt*16+ln][k = kh*32 + qd*8 + j] ----
    half8 bfr[4][2];
    #pragma unroll
    for (int nt = 0; nt < 4; ++nt)
        #pragma unroll
        for (int kh = 0; kh < 2; ++kh)
            bfr[nt][kh] = *(const half8*)(&w1t_s[nt * 16 + ln][kh * 32 + qd * 8]);

    // ================= Phase 1: all 21 tile logits, no recurrence =========
    float lg[NMT];
    #pragma unroll
    for (int k = 0; k < NMT; ++k) {
        unsigned pp = tab_s[k * 16 + ln];
        int fi = pp & 0xff, fj = pp >> 8;
        half8 x0 = *(const half8*)(&emb[fi][qd * 8])      * *(const half8*)(&emb[fj][qd * 8]);
        half8 x1 = *(const half8*)(&emb[fi][32 + qd * 8]) * *(const half8*)(&emb[fj][32 + qd * 8]);

        float lgp[4];
        #pragma unroll
        for (int nt = 0; nt < 4; ++nt) {
            f32x4 acc = { b1v4[nt].x, b1v4[nt].y, b1v4[nt].z, b1v4[nt].w };
            acc = __builtin_amdgcn_mfma_f32_16x16x32_f16(bfr[nt][0], x0, acc, 0, 0, 0);
            acc = __builtin_amdgcn_mfma_f32_16x16x32_f16(bfr[nt][1], x1, acc, 0, 0, 0);
            float u = fmaf(fmaxf(acc[1], 0.f), w2v4[nt].y, fmaxf(acc[0], 0.f) * w2v4[nt].x);
            float v = fmaf(fmaxf(acc[3], 0.f), w2v4[nt].w, fmaxf(acc[2], 0.f) * w2v4[nt].z);
            lgp[nt] = u + v;
        }
        float s = (lgp[0] + lgp[1]) + (lgp[2] + lgp[3]);
        s = qd_sum(s);                            // full 64-af logit, all lanes
        lg[k] = (k * 16 + ln >= NP) ? -INFINITY : s;
    }

    // ================= One softmax pass ====================================
    // per-lane max (4-way partial trees), then cross-ln max (bits 0..3)
    float mA = lg[0], mB = lg[1], mC = lg[2], mD = lg[3];
    #pragma unroll
    for (int k = 4; k + 3 < NMT; k += 4) {
        mA = fmaxf(mA, lg[k]);
        mB = fmaxf(mB, lg[k + 1]);
        mC = fmaxf(mC, lg[k + 2]);
        mD = fmaxf(mD, lg[k + 3]);
    }
    mA = fmaxf(mA, lg[20]);
    float mx = fmaxf(fmaxf(mA, mB), fmaxf(mC, mD));
    #pragma unroll
    for (int off = 1; off <= 8; off <<= 1) mx = fmaxf(mx, __shfl_xor(mx, off, 64));

    // e_k in place; 4-way partial sums
    float sA = 0.f, sB = 0.f, sC = 0.f, sD = 0.f;
    #pragma unroll
    for (int k = 0; k + 3 < NMT; k += 4) {
        lg[k]     = __expf(lg[k]     - mx);  sA += lg[k];
        lg[k + 1] = __expf(lg[k + 1] - mx);  sB += lg[k + 1];
        lg[k + 2] = __expf(lg[k + 2] - mx);  sC += lg[k + 2];
        lg[k + 3] = __expf(lg[k + 3] - mx);  sD += lg[k + 3];
    }
    lg[20] = __expf(lg[20] - mx);  sA += lg[20];
    float lsum = (sA + sB) + (sC + sD);
    #pragma unroll
    for (int off = 1; off <= 8; off <<= 1) lsum += __shfl_xor(lsum, off, 64);
    // lsum now uniform wave-wide (lg replicated across qd groups)

    // ================= Phase 2: acc += e_k * x_k (even/odd split) ==========
    half8 accA0 = bcast8(0.f), accA1 = bcast8(0.f);
    half8 accB0 = bcast8(0.f), accB1 = bcast8(0.f);
    #pragma unroll
    for (int k = 0; k < NMT; ++k) {
        unsigned pp = tab_s[k * 16 + ln];
        int fi = pp & 0xff, fj = pp >> 8;
        half8 x0 = *(const half8*)(&emb[fi][qd * 8])      * *(const half8*)(&emb[fj][qd * 8]);
        half8 x1 = *(const half8*)(&emb[fi][32 + qd * 8]) * *(const half8*)(&emb[fj][32 + qd * 8]);
        half8 e8 = bcast8(lg[k]);
        if (k & 1) { accB0 = accB0 + x0 * e8; accB1 = accB1 + x1 * e8; }
        else       { accA0 = accA0 + x0 * e8; accA1 = accA1 + x1 * e8; }
    }
    half8 acc0 = accA0 + accB0;
    half8 acc1 = accA1 + accB1;

    // ---- linear part (epilogue) ----
    float lin = 0.f;
    if (lane < NF) {
        lin = ltab[sparse[r * NF + lane]];
    } else if (lane >= 32 && lane < 32 + NDENSE) {
        int k = lane - 32;
        lin = dense[r * NDENSE + k] * wdense[k];
    }
    #pragma unroll
    for (int off = 32; off >= 1; off >>= 1) lin += __shfl_xor(lin, off, 64);
    lin += bias[0];

    // ---- proj-dot in-lane (dims qd*8..+7 and 32+qd*8..+7) ----
    float4 pa4 = *(const float4*)(proj + qd * 8);
    float4 pb4 = *(const float4*)(proj + qd * 8 + 4);
    float4 pc4 = *(const float4*)(proj + 32 + qd * 8);
    float4 pd4 = *(const float4*)(proj + 32 + qd * 8 + 4);
    float rr = (float)acc0[0] * pa4.x + (float)acc0[1] * pa4.y
             + (float)acc0[2] * pa4.z + (float)acc0[3] * pa4.w
             + (float)acc0[4] * pb4.x + (float)acc0[5] * pb4.y
             + (float)acc0[6] * pb4.z + (float)acc0[7] * pb4.w
             + (float)acc1[0] * pc4.x + (float)acc1[1] * pc4.y
             + (float)acc1[2] * pc4.z + (float)acc1[3] * pc4.w
             + (float)acc1[4] * pd4.x + (float)acc1[5] * pd4.y
             + (float)acc1[6] * pd4.z + (float)acc1[7] * pd4.w;
    // sum over ln (pairs) and qd (dim chunks): all 6 lane bits
    #pragma unroll
    for (int off = 1; off <= 32; off <<= 1) rr += __shfl_xor(rr, off, 64);

    if (lane == 0) out[r] = lin + rr / lsum;
}

extern "C" void kernel_launch(void* const* d_in, const int* in_sizes, int n_in,
                              void* d_out, int out_size, void* d_ws, size_t ws_size,
                              hipStream_t stream) {
    const int*   sparse = (const int*)  d_in[0];
    const float* dense  = (const float*)d_in[1];
    const float* etab   = (const float*)d_in[2];
    const float* ltab   = (const float*)d_in[3];
    const float* wdense = (const float*)d_in[4];
    const float* bias   = (const float*)d_in[5];
    const float* W1     = (const float*)d_in[6];
    const float* b1     = (const float*)d_in[7];
    const float* w2     = (const float*)d_in[8];
    const float* proj   = (const float*)d_in[9];
    float* outp = (float*)d_out;

    const int B = in_sizes[0] / NF;

    afm_kernel<<<dim3((B + WPB - 1) / WPB), dim3(BLOCK), 0, stream>>>(
        sparse, dense, etab, ltab, wdense, bias, W1, b1, w2, proj, outp, B);
    (void)n_in; (void)out_size; (void)d_ws; (void)ws_size;
}

// Round 7
// 113.190 us; speedup vs baseline: 1.0353x; 1.0353x over previous
//
#include <hip/hip_runtime.h>
#include <math.h>

// AFM forward: out[b] = linear(b) + softmax-weighted pair-interaction projection.
// B=4096, F=26, d=64, P=325 pairs, af=64.
//
// R14: 2 rows per wave (ILP-by-batching). Evidence: R12 (2x waves: null) and
// R13 (recurrence removed at cost of 2x LDS: -6.8us regression) show the main
// loop is a latency chain whose stalls neither TLP nor chain-restructuring can
// fill -- the wave simply has no other work to issue. Fix: give it some. Each
// wave runs TWO independent rows interleaved through the R11-proven skeleton
// (one-behind softmax pipeline, permlane qd_sum, launch_bounds(256,2)):
//   - per tile: 16 MFMAs (8/row), two independent logit trees, two
//     independent (m,l,acc) updates; chain-A stalls filled by chain-B issue.
//   - tab_s / bfr / b1+w2 fragments amortize over both rows; grid halves to
//     512 blocks so per-block W1 staging traffic halves chip-wide.
// Register budget ~165 VGPR (32 bfr + 32 b1/w2 + 64 frag/x + 16 acc + temps)
// under the 256 cap -> no spills (R10 falsifier: afm WRITE_SIZE stays ~KB).
// LDS ~40 KB/block -> 2 blocks/CU, 8 waves/CU (TLP proven non-binding).

#define NF 26
#define NP 325
#define NMT 21           // 21 m-tiles of 16 pairs (336, pads -> -inf)
#define ED 64
#define AF 64
#define NDENSE 13
#define RPW 2            // rows per wave (the R14 lever)
#define WPB 4            // waves per block
#define RPB (WPB * RPW)  // 8 rows per block
#define BLOCK (WPB * 64)
#define ESTRIDE 72       // f16 elems per emb row: 144 B (16B-aligned rows)
#define WSTRIDE 72       // f16 elems per w1t row: 144 B (16B-aligned rows)

typedef __attribute__((ext_vector_type(8))) _Float16 half8;
typedef __attribute__((ext_vector_type(4))) float f32x4;

__device__ __forceinline__ half8 bcast8(float v) {
    _Float16 hh = (_Float16)v;
    half8 r = { hh, hh, hh, hh, hh, hh, hh, hh };
    return r;
}

// Sum across the qd lane-groups (lane bits 4,5). permlane*_swap runs on the
// VALU pipe (no lgkmcnt interaction); swap(x,x) returns (even-group bcast,
// odd-group bcast), so r0+r1 = xor-sum, uniform across lanes.
__device__ __forceinline__ float qd_sum(float x) {
#if __has_builtin(__builtin_amdgcn_permlane16_swap) && __has_builtin(__builtin_amdgcn_permlane32_swap)
    {
        auto a = __builtin_amdgcn_permlane16_swap(__builtin_bit_cast(unsigned, x),
                                                  __builtin_bit_cast(unsigned, x),
                                                  false, false);
        x = __builtin_bit_cast(float, a[0]) + __builtin_bit_cast(float, a[1]);
        auto b = __builtin_amdgcn_permlane32_swap(__builtin_bit_cast(unsigned, x),
                                                  __builtin_bit_cast(unsigned, x),
                                                  false, false);
        x = __builtin_bit_cast(float, b[0]) + __builtin_bit_cast(float, b[1]);
    }
#else
    x += __shfl_xor(x, 16, 64);
    x += __shfl_xor(x, 32, 64);
#endif
    return x;
}

__global__ __launch_bounds__(BLOCK, 2)   // cap 256 VGPR: spills are the enemy (R10)
void afm_kernel(const int*   __restrict__ sparse,   // [B,26]
                const float* __restrict__ dense,    // [B,13]
                const float* __restrict__ etab,     // [V,64]
                const float* __restrict__ ltab,     // [V]
                const float* __restrict__ wdense,   // [13]
                const float* __restrict__ bias,     // [1]
                const float* __restrict__ W1,       // [64][64] f32, d-major
                const float* __restrict__ b1,       // [64]
                const float* __restrict__ w2,       // [64]
                const float* __restrict__ proj,     // [64]
                float*       __restrict__ out,      // [B]
                int B)
{
    const int t    = threadIdx.x;
    const int wave = t >> 6;
    const int lane = t & 63;
    const int qd   = lane >> 4;     // quad 0..3
    const int ln   = lane & 15;

    __shared__ alignas(16) _Float16       w1t_s[AF][WSTRIDE];        //  9216 B
    __shared__              unsigned short tab_s[NMT * 16];          //   672 B
    __shared__ alignas(16) _Float16       emb_all[RPB][NF][ESTRIDE]; // 29952 B

    // ---- block-cooperative embedding staging: RPB rows spread evenly over
    //      256 threads (1664 tasks), f32 gather -> f16 b128 LDS writes ----
    for (int task = t; task < RPB * NF * 8; task += BLOCK) {
        int w   = task / (NF * 8);
        int rem = task - w * (NF * 8);
        int f = rem >> 3, c = rem & 7;                   // 8-half chunk
        int rw = blockIdx.x * RPB + w;
        if (rw < B) {
            const float* src = etab + (size_t)sparse[rw * NF + f] * ED + c * 8;
            float4 v0 = *(const float4*)(src);
            float4 v1 = *(const float4*)(src + 4);
            half8 hv = { (_Float16)v0.x, (_Float16)v0.y, (_Float16)v0.z, (_Float16)v0.w,
                         (_Float16)v1.x, (_Float16)v1.y, (_Float16)v1.z, (_Float16)v1.w };
            *(half8*)(&emb_all[w][f][c * 8]) = hv;
        }
    }
    // ---- block-cooperative W1 -> W1^T staging (L2-hot 16 KB) ----
    for (int idx = t; idx < ED * AF; idx += BLOCK) {
        int d = idx >> 6, a = idx & 63;       // W1 is [d][a]
        w1t_s[a][d] = (_Float16)W1[idx];
    }
    // ---- pair-index table: tab_s[p] = i | j<<8 (slots >= NP stay 0) ----
    for (int p = t; p < NMT * 16; p += BLOCK) {
        unsigned short v = 0;
        if (p < NP) {
            int rem = p, i = 0;
            while (rem >= NF - 1 - i) { rem -= NF - 1 - i; ++i; }
            v = (unsigned short)(i | ((i + 1 + rem) << 8));
        }
        tab_s[p] = v;
    }

    const int rA = blockIdx.x * RPB + wave * RPW;   // this wave's two rows
    const int rB = rA + 1;
    const bool actA = (rA < B);
    const bool actB = (rB < B);

    _Float16 (* __restrict__ embA)[ESTRIDE] = emb_all[wave * RPW];
    _Float16 (* __restrict__ embB)[ESTRIDE] = emb_all[wave * RPW + (actB ? 1 : 0)];

    __syncthreads();          // w1t_s/tab_s/emb_all visible
    if (!actA) return;        // safe: no barriers after this point

    // b1/w2 for af = nt*16 + qd*4 + rr  (C-row mapping) -- shared by both rows
    float4 b1v4[4], w2v4[4];
    #pragma unroll
    for (int nt = 0; nt < 4; ++nt) {
        b1v4[nt] = *(const float4*)(b1 + nt * 16 + qd * 4);
        w2v4[nt] = *(const float4*)(w2 + nt * 16 + qd * 4);
    }

    // ---- W1^T A-operand fragments from LDS (shared by both rows):
    //      bfr[nt][kh] = w1t[af = nt*16+ln][k = kh*32 + qd*8 + j] ----
    half8 bfr[4][2];
    #pragma unroll
    for (int nt = 0; nt < 4; ++nt)
        #pragma unroll
        for (int kh = 0; kh < 2; ++kh)
            bfr[nt][kh] = *(const half8*)(&w1t_s[nt * 16 + ln][kh * 32 + qd * 8]);

    // ---- fused main loop: two independent rows interleaved, each with the
    //      R11 one-behind softmax pipeline. ----
    float mA = -INFINITY, lA = 0.f;
    float mB = -INFINITY, lB = 0.f;
    half8 accA0 = bcast8(0.f), accA1 = bcast8(0.f);
    half8 accB0 = bcast8(0.f), accB1 = bcast8(0.f);

    unsigned pp0 = tab_s[ln];
    int fi0 = pp0 & 0xff, fj0 = pp0 >> 8;
    half8 eiA0 = *(const half8*)(&embA[fi0][qd * 8]);
    half8 eiA1 = *(const half8*)(&embA[fi0][32 + qd * 8]);
    half8 ejA0 = *(const half8*)(&embA[fj0][qd * 8]);
    half8 ejA1 = *(const half8*)(&embA[fj0][32 + qd * 8]);
    half8 eiB0 = *(const half8*)(&embB[fi0][qd * 8]);
    half8 eiB1 = *(const half8*)(&embB[fi0][32 + qd * 8]);
    half8 ejB0 = *(const half8*)(&embB[fj0][qd * 8]);
    half8 ejB1 = *(const half8*)(&embB[fj0][32 + qd * 8]);

    float lgPA = 0.f, lgPB = 0.f;
    half8 xPA0 = bcast8(0.f), xPA1 = bcast8(0.f);
    half8 xPB0 = bcast8(0.f), xPB1 = bcast8(0.f);

    for (int k = 0; k < NMT; ++k) {
        // finish L(k): build both rows' pair products (waits on frag loads)
        half8 xA0 = eiA0 * ejA0;
        half8 xA1 = eiA1 * ejA1;
        half8 xB0 = eiB0 * ejB0;
        half8 xB1 = eiB1 * ejB1;

        // issue L(k+1): next tile's fragment loads, both rows (tab read once)
        if (k + 1 < NMT) {
            unsigned np = tab_s[(k + 1) * 16 + ln];
            int nfi = np & 0xff, nfj = np >> 8;
            eiA0 = *(const half8*)(&embA[nfi][qd * 8]);
            eiA1 = *(const half8*)(&embA[nfi][32 + qd * 8]);
            ejA0 = *(const half8*)(&embA[nfj][qd * 8]);
            ejA1 = *(const half8*)(&embA[nfj][32 + qd * 8]);
            eiB0 = *(const half8*)(&embB[nfi][qd * 8]);
            eiB1 = *(const half8*)(&embB[nfi][32 + qd * 8]);
            ejB0 = *(const half8*)(&embB[nfj][qd * 8]);
            ejB1 = *(const half8*)(&embB[nfj][32 + qd * 8]);
        }

        // G(k): logits for both rows. D[m=af][n=pair=ln]; C rows = qd*4+reg.
        float lgpA[4], lgpB[4];
        #pragma unroll
        for (int nt = 0; nt < 4; ++nt) {
            f32x4 ca = { b1v4[nt].x, b1v4[nt].y, b1v4[nt].z, b1v4[nt].w };
            ca = __builtin_amdgcn_mfma_f32_16x16x32_f16(bfr[nt][0], xA0, ca, 0, 0, 0);
            ca = __builtin_amdgcn_mfma_f32_16x16x32_f16(bfr[nt][1], xA1, ca, 0, 0, 0);
            f32x4 cb = { b1v4[nt].x, b1v4[nt].y, b1v4[nt].z, b1v4[nt].w };
            cb = __builtin_amdgcn_mfma_f32_16x16x32_f16(bfr[nt][0], xB0, cb, 0, 0, 0);
            cb = __builtin_amdgcn_mfma_f32_16x16x32_f16(bfr[nt][1], xB1, cb, 0, 0, 0);
            float ua = fmaf(fmaxf(ca[1], 0.f), w2v4[nt].y, fmaxf(ca[0], 0.f) * w2v4[nt].x);
            float va = fmaf(fmaxf(ca[3], 0.f), w2v4[nt].w, fmaxf(ca[2], 0.f) * w2v4[nt].z);
            lgpA[nt] = ua + va;
            float ub = fmaf(fmaxf(cb[1], 0.f), w2v4[nt].y, fmaxf(cb[0], 0.f) * w2v4[nt].x);
            float vb = fmaf(fmaxf(cb[3], 0.f), w2v4[nt].w, fmaxf(cb[2], 0.f) * w2v4[nt].z);
            lgpB[nt] = ub + vb;
        }
        float lgA = (lgpA[0] + lgpA[1]) + (lgpA[2] + lgpA[3]);
        float lgB = (lgpB[0] + lgpB[1]) + (lgpB[2] + lgpB[3]);
        lgA = qd_sum(lgA);                       // full 64-af logit, all lanes
        lgB = qd_sum(lgB);
        if (k * 16 + ln >= NP) { lgA = -INFINITY; lgB = -INFINITY; }

        // S(k-1): the two serial updates -- independent, mutually stall-filling
        if (k > 0) {
            float mnA    = fmaxf(mA, lgPA);
            float mnB    = fmaxf(mB, lgPB);
            float alphaA = __expf(mA - mnA);     // mA=-inf first time -> 0
            float alphaB = __expf(mB - mnB);
            float eA     = __expf(lgPA - mnA);
            float eB     = __expf(lgPB - mnB);
            lA = lA * alphaA + eA;
            lB = lB * alphaB + eB;
            mA = mnA;
            mB = mnB;
            half8 a8A = bcast8(alphaA), e8A = bcast8(eA);
            half8 a8B = bcast8(alphaB), e8B = bcast8(eB);
            accA0 = accA0 * a8A + xPA0 * e8A;    // v_pk_fma_f16
            accA1 = accA1 * a8A + xPA1 * e8A;
            accB0 = accB0 * a8B + xPB0 * e8B;
            accB1 = accB1 * a8B + xPB1 * e8B;
        }
        // rotate pipeline state
        xPA0 = xA0; xPA1 = xA1; lgPA = lgA;
        xPB0 = xB0; xPB1 = xB1; lgPB = lgB;
    }
    // S(NMT-1): drain both pipelines
    {
        float mnA    = fmaxf(mA, lgPA);
        float mnB    = fmaxf(mB, lgPB);
        float alphaA = __expf(mA - mnA);
        float alphaB = __expf(mB - mnB);
        float eA     = __expf(lgPA - mnA);
        float eB     = __expf(lgPB - mnB);
        lA = lA * alphaA + eA;
        lB = lB * alphaB + eB;
        mA = mnA;
        mB = mnB;
        half8 a8A = bcast8(alphaA), e8A = bcast8(eA);
        half8 a8B = bcast8(alphaB), e8B = bcast8(eB);
        accA0 = accA0 * a8A + xPA0 * e8A;
        accA1 = accA1 * a8A + xPA1 * e8A;
        accB0 = accB0 * a8B + xPB0 * e8B;
        accB1 = accB1 * a8B + xPB1 * e8B;
    }

    // ---- merges: lanes sharing qd (ln bits) cover all 336 slots per row ----
    float mgA = mA, mgB = mB;
    #pragma unroll
    for (int off = 1; off <= 8; off <<= 1) {
        mgA = fmaxf(mgA, __shfl_xor(mgA, off, 64));
        mgB = fmaxf(mgB, __shfl_xor(mgB, off, 64));
    }
    const float facA = __expf(mA - mgA);         // per-lane rescale to global max
    const float facB = __expf(mB - mgB);
    float lsumA = lA * facA, lsumB = lB * facB;
    #pragma unroll
    for (int off = 1; off <= 8; off <<= 1) {
        lsumA += __shfl_xor(lsumA, off, 64);
        lsumB += __shfl_xor(lsumB, off, 64);
    }

    // proj-dot in-lane (dims qd*8..+7 and 32+qd*8..+7), scaled by fac
    float4 pa4 = *(const float4*)(proj + qd * 8);
    float4 pb4 = *(const float4*)(proj + qd * 8 + 4);
    float4 pc4 = *(const float4*)(proj + 32 + qd * 8);
    float4 pd4 = *(const float4*)(proj + 32 + qd * 8 + 4);
    float rrA = (float)accA0[0] * pa4.x + (float)accA0[1] * pa4.y
              + (float)accA0[2] * pa4.z + (float)accA0[3] * pa4.w
              + (float)accA0[4] * pb4.x + (float)accA0[5] * pb4.y
              + (float)accA0[6] * pb4.z + (float)accA0[7] * pb4.w
              + (float)accA1[0] * pc4.x + (float)accA1[1] * pc4.y
              + (float)accA1[2] * pc4.z + (float)accA1[3] * pc4.w
              + (float)accA1[4] * pd4.x + (float)accA1[5] * pd4.y
              + (float)accA1[6] * pd4.z + (float)accA1[7] * pd4.w;
    float rrB = (float)accB0[0] * pa4.x + (float)accB0[1] * pa4.y
              + (float)accB0[2] * pa4.z + (float)accB0[3] * pa4.w
              + (float)accB0[4] * pb4.x + (float)accB0[5] * pb4.y
              + (float)accB0[6] * pb4.z + (float)accB0[7] * pb4.w
              + (float)accB1[0] * pc4.x + (float)accB1[1] * pc4.y
              + (float)accB1[2] * pc4.z + (float)accB1[3] * pc4.w
              + (float)accB1[4] * pd4.x + (float)accB1[5] * pd4.y
              + (float)accB1[6] * pd4.z + (float)accB1[7] * pd4.w;
    rrA *= facA;
    rrB *= facB;
    // sum over ln (pairs) and qd (dim chunks): all 6 lane bits
    #pragma unroll
    for (int off = 1; off <= 32; off <<= 1) {
        rrA += __shfl_xor(rrA, off, 64);
        rrB += __shfl_xor(rrB, off, 64);
    }

    // ---- linear parts (epilogue) ----
    float linA = 0.f, linB = 0.f;
    if (lane < NF) {
        linA = ltab[sparse[rA * NF + lane]];
        if (actB) linB = ltab[sparse[rB * NF + lane]];
    } else if (lane >= 32 && lane < 32 + NDENSE) {
        int k = lane - 32;
        linA = dense[rA * NDENSE + k] * wdense[k];
        if (actB) linB = dense[rB * NDENSE + k] * wdense[k];
    }
    #pragma unroll
    for (int off = 32; off >= 1; off >>= 1) {
        linA += __shfl_xor(linA, off, 64);
        linB += __shfl_xor(linB, off, 64);
    }
    linA += bias[0];
    linB += bias[0];

    if (lane == 0) {
        out[rA] = linA + rrA / lsumA;
        if (actB) out[rB] = linB + rrB / lsumB;
    }
}

extern "C" void kernel_launch(void* const* d_in, const int* in_sizes, int n_in,
                              void* d_out, int out_size, void* d_ws, size_t ws_size,
                              hipStream_t stream) {
    const int*   sparse = (const int*)  d_in[0];
    const float* dense  = (const float*)d_in[1];
    const float* etab   = (const float*)d_in[2];
    const float* ltab   = (const float*)d_in[3];
    const float* wdense = (const float*)d_in[4];
    const float* bias   = (const float*)d_in[5];
    const float* W1     = (const float*)d_in[6];
    const float* b1     = (const float*)d_in[7];
    const float* w2     = (const float*)d_in[8];
    const float* proj   = (const float*)d_in[9];
    float* outp = (float*)d_out;

    const int B = in_sizes[0] / NF;

    afm_kernel<<<dim3((B + RPB - 1) / RPB), dim3(BLOCK), 0, stream>>>(
        sparse, dense, etab, ltab, wdense, bias, W1, b1, w2, proj, outp, B);
    (void)n_in; (void)out_size; (void)d_ws; (void)ws_size;
}

// Round 8
// 112.546 us; speedup vs baseline: 1.0413x; 1.0057x over previous
//
#include <hip/hip_runtime.h>
#include <math.h>

// AFM forward: out[b] = linear(b) + softmax-weighted pair-interaction projection.
// B=4096, F=26, d=64, P=325 pairs, af=64.
//
// R15: revert to the R11 structure (best measured: 110.4 total, afm ~33 us)
// + two mechanism-backed micro-opts. Post-mortems R12-R14: all structural
// alternatives lose to R11 (TLP null; two-phase -7us; 2-rows/wave -3us) --
// the loop is a latency chain near its VALU-issue floor and ~77us of total
// is harness fill/gap overhead. Changes vs R11:
//  (a) MFMAs issue as one pure 8-MFMA cluster wrapped in s_setprio(1)/(0)
//      (independent-wave structure = the attn-like case where setprio
//      measured +4-7%; null only for barrier-lockstep loops).
//  (b) exp2-domain softmax: w2 pre-scaled by log2(e) (softmax invariant
//      under uniform logit scale + matching base), all __expf -> exp2f,
//      deleting the hidden x*log2e mul inside every exp.
// Everything else identical to R11: 1 row/wave, 4 waves/block, grid 1024,
// block-cooperative prologue, permlane qd_sum, one-behind softmax pipeline,
// launch_bounds(256,2) (R10 lesson: spills are the enemy).

#define NF 26
#define NP 325
#define NMT 21           // 21 m-tiles of 16 pairs (336, pads -> -inf)
#define ED 64
#define AF 64
#define NDENSE 13
#define WPB 4            // waves (rows) per block
#define BLOCK (WPB * 64)
#define ESTRIDE 72       // f16 elems per emb row: 144 B (16B-aligned rows)
#define WSTRIDE 72       // f16 elems per w1t row: 144 B (16B-aligned rows)
#define LOG2E 1.44269504088896340736f

typedef __attribute__((ext_vector_type(8))) _Float16 half8;
typedef __attribute__((ext_vector_type(4))) float f32x4;

__device__ __forceinline__ half8 bcast8(float v) {
    _Float16 hh = (_Float16)v;
    half8 r = { hh, hh, hh, hh, hh, hh, hh, hh };
    return r;
}

// Sum across the qd lane-groups (lane bits 4,5). permlane*_swap runs on the
// VALU pipe (no lgkmcnt interaction); swap(x,x) returns (even-group bcast,
// odd-group bcast), so r0+r1 = xor-sum, uniform across lanes.
__device__ __forceinline__ float qd_sum(float x) {
#if __has_builtin(__builtin_amdgcn_permlane16_swap) && __has_builtin(__builtin_amdgcn_permlane32_swap)
    {
        auto a = __builtin_amdgcn_permlane16_swap(__builtin_bit_cast(unsigned, x),
                                                  __builtin_bit_cast(unsigned, x),
                                                  false, false);
        x = __builtin_bit_cast(float, a[0]) + __builtin_bit_cast(float, a[1]);
        auto b = __builtin_amdgcn_permlane32_swap(__builtin_bit_cast(unsigned, x),
                                                  __builtin_bit_cast(unsigned, x),
                                                  false, false);
        x = __builtin_bit_cast(float, b[0]) + __builtin_bit_cast(float, b[1]);
    }
#else
    x += __shfl_xor(x, 16, 64);
    x += __shfl_xor(x, 32, 64);
#endif
    return x;
}

__global__ __launch_bounds__(BLOCK, 2)   // cap 256 VGPR: spills are the enemy (R10)
void afm_kernel(const int*   __restrict__ sparse,   // [B,26]
                const float* __restrict__ dense,    // [B,13]
                const float* __restrict__ etab,     // [V,64]
                const float* __restrict__ ltab,     // [V]
                const float* __restrict__ wdense,   // [13]
                const float* __restrict__ bias,     // [1]
                const float* __restrict__ W1,       // [64][64] f32, d-major
                const float* __restrict__ b1,       // [64]
                const float* __restrict__ w2,       // [64]
                const float* __restrict__ proj,     // [64]
                float*       __restrict__ out,      // [B]
                int B)
{
    const int t    = threadIdx.x;
    const int wave = t >> 6;
    const int lane = t & 63;
    const int qd   = lane >> 4;     // quad 0..3
    const int ln   = lane & 15;

    __shared__ alignas(16) _Float16       w1t_s[AF][WSTRIDE];        // 9216 B
    __shared__              unsigned short tab_s[NMT * 16];          //  672 B
    __shared__ alignas(16) _Float16       emb_all[WPB][NF][ESTRIDE]; // 14976 B

    // ---- block-cooperative embedding staging: WPB rows spread evenly over
    //      256 threads (832 tasks), f32 gather -> f16 b128 LDS writes ----
    for (int task = t; task < WPB * NF * 8; task += BLOCK) {
        int w   = task / (NF * 8);
        int rem = task - w * (NF * 8);
        int f = rem >> 3, c = rem & 7;                   // 8-half chunk
        int rw = blockIdx.x * WPB + w;
        if (rw < B) {
            const float* src = etab + (size_t)sparse[rw * NF + f] * ED + c * 8;
            float4 v0 = *(const float4*)(src);
            float4 v1 = *(const float4*)(src + 4);
            half8 hv = { (_Float16)v0.x, (_Float16)v0.y, (_Float16)v0.z, (_Float16)v0.w,
                         (_Float16)v1.x, (_Float16)v1.y, (_Float16)v1.z, (_Float16)v1.w };
            *(half8*)(&emb_all[w][f][c * 8]) = hv;
        }
    }
    // ---- block-cooperative W1 -> W1^T staging (L2-hot 16 KB) ----
    for (int idx = t; idx < ED * AF; idx += BLOCK) {
        int d = idx >> 6, a = idx & 63;       // W1 is [d][a]
        w1t_s[a][d] = (_Float16)W1[idx];
    }
    // ---- pair-index table: tab_s[p] = i | j<<8 (slots >= NP stay 0) ----
    for (int p = t; p < NMT * 16; p += BLOCK) {
        unsigned short v = 0;
        if (p < NP) {
            int rem = p, i = 0;
            while (rem >= NF - 1 - i) { rem -= NF - 1 - i; ++i; }
            v = (unsigned short)(i | ((i + 1 + rem) << 8));
        }
        tab_s[p] = v;
    }

    const int r = blockIdx.x * WPB + wave;   // this wave's batch row
    const bool active = (r < B);

    _Float16 (* __restrict__ emb)[ESTRIDE] = emb_all[wave];

    __syncthreads();          // w1t_s/tab_s/emb_all visible
    if (!active) return;      // safe: no barriers after this point

    // b1/w2 for af = nt*16 + qd*4 + rr  (C-row mapping).
    // w2 pre-scaled by log2(e): logits live in the exp2 domain from here on
    // (softmax invariant under uniform logit scale with matching base).
    float4 b1v4[4], w2v4[4];
    #pragma unroll
    for (int nt = 0; nt < 4; ++nt) {
        b1v4[nt] = *(const float4*)(b1 + nt * 16 + qd * 4);
        float4 w = *(const float4*)(w2 + nt * 16 + qd * 4);
        w2v4[nt].x = w.x * LOG2E;
        w2v4[nt].y = w.y * LOG2E;
        w2v4[nt].z = w.z * LOG2E;
        w2v4[nt].w = w.w * LOG2E;
    }

    // ---- W1^T A-operand fragments from LDS:
    //      bfr[nt][kh] = w1t[af = nt*16+ln][k = kh*32 + qd*8 + j] ----
    half8 bfr[4][2];
    #pragma unroll
    for (int nt = 0; nt < 4; ++nt)
        #pragma unroll
        for (int kh = 0; kh < 2; ++kh)
            bfr[nt][kh] = *(const half8*)(&w1t_s[nt * 16 + ln][kh * 32 + qd * 8]);

    // ---- fused main loop, software-pipelined: G(k) computes tile-k logit
    //      while S(k-1) performs the serial softmax/accumulator update. ----
    float m = -INFINITY, l = 0.f;
    half8 acc0 = bcast8(0.f), acc1 = bcast8(0.f);

    unsigned pp0 = tab_s[ln];
    int fi0 = pp0 & 0xff, fj0 = pp0 >> 8;
    half8 eiR0 = *(const half8*)(&emb[fi0][qd * 8]);
    half8 eiR1 = *(const half8*)(&emb[fi0][32 + qd * 8]);
    half8 ejR0 = *(const half8*)(&emb[fj0][qd * 8]);
    half8 ejR1 = *(const half8*)(&emb[fj0][32 + qd * 8]);

    float lgP = 0.f;
    half8 xP0 = bcast8(0.f), xP1 = bcast8(0.f);

    for (int k = 0; k < NMT; ++k) {
        // finish L(k): build current pair products (waits on frag loads)
        half8 xC0 = eiR0 * ejR0;
        half8 xC1 = eiR1 * ejR1;

        // issue L(k+1): next tile's fragment loads
        if (k + 1 < NMT) {
            unsigned np = tab_s[(k + 1) * 16 + ln];
            int nfi = np & 0xff, nfj = np >> 8;
            eiR0 = *(const half8*)(&emb[nfi][qd * 8]);
            eiR1 = *(const half8*)(&emb[nfi][32 + qd * 8]);
            ejR0 = *(const half8*)(&emb[nfj][qd * 8]);
            ejR1 = *(const half8*)(&emb[nfj][32 + qd * 8]);
        }

        // G(k) part 1: pure 8-MFMA cluster under raised priority.
        f32x4 cacc[4];
        __builtin_amdgcn_s_setprio(1);
        #pragma unroll
        for (int nt = 0; nt < 4; ++nt) {
            f32x4 acc = { b1v4[nt].x, b1v4[nt].y, b1v4[nt].z, b1v4[nt].w };
            acc = __builtin_amdgcn_mfma_f32_16x16x32_f16(bfr[nt][0], xC0, acc, 0, 0, 0);
            acc = __builtin_amdgcn_mfma_f32_16x16x32_f16(bfr[nt][1], xC1, acc, 0, 0, 0);
            cacc[nt] = acc;
        }
        __builtin_amdgcn_s_setprio(0);

        // G(k) part 2: relu + w2-dot tree. D rows = qd*4+reg = af in nt*16.
        float lgp[4];
        #pragma unroll
        for (int nt = 0; nt < 4; ++nt) {
            float u = fmaf(fmaxf(cacc[nt][1], 0.f), w2v4[nt].y,
                           fmaxf(cacc[nt][0], 0.f) * w2v4[nt].x);
            float v = fmaf(fmaxf(cacc[nt][3], 0.f), w2v4[nt].w,
                           fmaxf(cacc[nt][2], 0.f) * w2v4[nt].z);
            lgp[nt] = u + v;
        }
        float lg = (lgp[0] + lgp[1]) + (lgp[2] + lgp[3]);
        lg = qd_sum(lg);                         // full 64-af logit (log2 domain)
        if (k * 16 + ln >= NP) lg = -INFINITY;   // pad pairs contribute 0

        // S(k-1): serial online-softmax update (the only loop recurrence)
        if (k > 0) {
            float mn    = fmaxf(m, lgP);
            float alpha = exp2f(m - mn);         // m=-inf first time -> 0
            float e     = exp2f(lgP - mn);       // lgP=-inf pad -> 0
            l = l * alpha + e;
            m = mn;
            half8 a8 = bcast8(alpha), e8 = bcast8(e);
            acc0 = acc0 * a8 + xP0 * e8;         // v_pk_fma_f16
            acc1 = acc1 * a8 + xP1 * e8;
        }
        // rotate pipeline state
        xP0 = xC0; xP1 = xC1; lgP = lg;
    }
    // S(NMT-1): drain the pipeline
    {
        float mn    = fmaxf(m, lgP);
        float alpha = exp2f(m - mn);
        float e     = exp2f(lgP - mn);
        l = l * alpha + e;
        m = mn;
        half8 a8 = bcast8(alpha), e8 = bcast8(e);
        acc0 = acc0 * a8 + xP0 * e8;
        acc1 = acc1 * a8 + xP1 * e8;
    }

    // ---- linear part (epilogue; overlaps the merge below) ----
    float lin = 0.f;
    if (lane < NF) {
        lin = ltab[sparse[r * NF + lane]];
    } else if (lane >= 32 && lane < 32 + NDENSE) {
        int k = lane - 32;
        lin = dense[r * NDENSE + k] * wdense[k];
    }
    #pragma unroll
    for (int off = 32; off >= 1; off >>= 1) lin += __shfl_xor(lin, off, 64);
    lin += bias[0];

    // ---- merge: lanes sharing qd (ln = bits 0..3) cover all 336 slots ----
    float mg = m;
    #pragma unroll
    for (int off = 1; off <= 8; off <<= 1) mg = fmaxf(mg, __shfl_xor(mg, off, 64));
    const float fac = exp2f(m - mg);             // per-lane rescale to global max
    float lsum = l * fac;
    #pragma unroll
    for (int off = 1; off <= 8; off <<= 1) lsum += __shfl_xor(lsum, off, 64);
    // lsum now = global softmax denominator, identical across qd groups

    // proj-dot in-lane (dims qd*8..+7 and 32+qd*8..+7), scaled by fac
    float4 pa4 = *(const float4*)(proj + qd * 8);
    float4 pb4 = *(const float4*)(proj + qd * 8 + 4);
    float4 pc4 = *(const float4*)(proj + 32 + qd * 8);
    float4 pd4 = *(const float4*)(proj + 32 + qd * 8 + 4);
    float rr = (float)acc0[0] * pa4.x + (float)acc0[1] * pa4.y
             + (float)acc0[2] * pa4.z + (float)acc0[3] * pa4.w
             + (float)acc0[4] * pb4.x + (float)acc0[5] * pb4.y
             + (float)acc0[6] * pb4.z + (float)acc0[7] * pb4.w
             + (float)acc1[0] * pc4.x + (float)acc1[1] * pc4.y
             + (float)acc1[2] * pc4.z + (float)acc1[3] * pc4.w
             + (float)acc1[4] * pd4.x + (float)acc1[5] * pd4.y
             + (float)acc1[6] * pd4.z + (float)acc1[7] * pd4.w;
    rr *= fac;
    // sum over ln (pairs) and qd (dim chunks): all 6 lane bits
    #pragma unroll
    for (int off = 1; off <= 32; off <<= 1) rr += __shfl_xor(rr, off, 64);

    if (lane == 0) out[r] = lin + rr / lsum;
}

extern "C" void kernel_launch(void* const* d_in, const int* in_sizes, int n_in,
                              void* d_out, int out_size, void* d_ws, size_t ws_size,
                              hipStream_t stream) {
    const int*   sparse = (const int*)  d_in[0];
    const float* dense  = (const float*)d_in[1];
    const float* etab   = (const float*)d_in[2];
    const float* ltab   = (const float*)d_in[3];
    const float* wdense = (const float*)d_in[4];
    const float* bias   = (const float*)d_in[5];
    const float* W1     = (const float*)d_in[6];
    const float* b1     = (const float*)d_in[7];
    const float* w2     = (const float*)d_in[8];
    const float* proj   = (const float*)d_in[9];
    float* outp = (float*)d_out;

    const int B = in_sizes[0] / NF;

    afm_kernel<<<dim3((B + WPB - 1) / WPB), dim3(BLOCK), 0, stream>>>(
        sparse, dense, etab, ltab, wdense, bias, W1, b1, w2, proj, outp, B);
    (void)n_in; (void)out_size; (void)d_ws; (void)ws_size;
}